// Round 1
// 267.290 us; speedup vs baseline: 1.0465x; 1.0465x over previous
//
#include <hip/hip_runtime.h>
#include <math.h>

typedef unsigned short ushort_t;
typedef __bf16 bf16x8 __attribute__((ext_vector_type(8)));
typedef ushort_t ushort8v __attribute__((ext_vector_type(8)));
typedef float f32x4 __attribute__((ext_vector_type(4)));

#define B_SZ   4
#define SEQ    8192
#define M_ROWS (B_SZ * SEQ)   // 32768
#define CH     128
#define NC     (SEQ / CH)     // 64

__device__ __forceinline__ ushort_t f2bf(float f) {
    unsigned u = __float_as_uint(f);
    u = u + 0x7fffu + ((u >> 16) & 1u);
    return (ushort_t)(u >> 16);
}
__device__ __forceinline__ float bf2f(ushort_t b) {
    return __uint_as_float(((unsigned)b) << 16);
}

__device__ __forceinline__ void load16_lds(const void* g, void* l) {
    __builtin_amdgcn_global_load_lds(
        (const __attribute__((address_space(1))) unsigned int*)g,
        (__attribute__((address_space(3))) unsigned int*)l, 16, 0, 0);
}

__device__ __forceinline__ bf16x8 ldfrag(const ushort_t* p) {
    union { ushort8v u; bf16x8 b; } cv;
    cv.u = *(const ushort8v*)p;
    return cv.b;
}

// ---------------------------------------------------------------------------
// prep / conv_x unchanged from previous round.
__global__ void prep_kernel(const float* __restrict__ Lre,
                            const float* __restrict__ Lim,
                            const float* __restrict__ ldt,
                            const float* __restrict__ Bre,
                            const float* __restrict__ Bim,
                            const float* __restrict__ Cre,
                            const float* __restrict__ Cim,
                            float* __restrict__ abar,
                            float* __restrict__ apow,
                            ushort_t* __restrict__ Bmat,
                            ushort_t* __restrict__ Cmat) {
    int idx = blockIdx.x * 256 + threadIdx.x;   // 0 .. 262143
    int h = idx & 511;
    int p = (idx >> 9) & 255;
    int d = idx >> 17;
    int ip = d * 256 + p;
    float lr = Lre[ip], li = Lim[ip];
    float dt = expf(ldt[ip]);
    float e   = expf(lr * dt);
    float ang = li * dt;
    float ar = e * cosf(ang), ai = e * sinf(ang);
    float nr = ar - 1.0f, ni = ai;
    float den = lr * lr + li * li;
    float cr = (nr * lr + ni * li) / den;
    float ci = (ni * lr - nr * li) / den;
    float br = Bre[idx], bi = Bim[idx];
    Bmat[(d * 512 + 2 * p) * 512 + h]     = f2bf(cr * br - ci * bi);
    Bmat[(d * 512 + 2 * p + 1) * 512 + h] = f2bf(cr * bi + ci * br);
    if (h == 0) {
        int o = d * 512 + 2 * p;
        abar[o] = ar;  abar[o + 1] = ai;
        float eC = expf(lr * dt * (float)CH);
        float aC = ang * (float)CH;
        apow[o] = eC * cosf(aC);  apow[o + 1] = eC * sinf(aC);
    }
    int p2 = idx & 255;
    int h2 = (idx >> 8) & 511;
    int d2 = idx >> 17;
    Cmat[h2 * 1024 + d2 * 512 + 2 * p2]     = f2bf(Cre[idx]);
    Cmat[h2 * 1024 + d2 * 512 + 2 * p2 + 1] = f2bf(-Cim[idx]);
}

__global__ void conv_x_kernel(const float* __restrict__ x,
                              ushort_t* __restrict__ X16) {
    int i = blockIdx.x * 256 + threadIdx.x;
    float4 v = ((const float4*)x)[i];
    ushort_t o[4] = {f2bf(v.x), f2bf(v.y), f2bf(v.z), f2bf(v.w)};
    *(uint2*)&X16[(size_t)i * 4] = *(const uint2*)o;
}

// ---------------------------------------------------------------------------
// 256x256 8-phase bf16 GEMM (T2+T3+T4+T5 port, plain HIP).
//   BM=BN=256, BK=64 (2 k-slices of 32), 512 threads = 8 waves (2M x 4N),
//   per-wave output 128x64 -> acc[8][4] f32x4 (128 VGPRs).
// LDS: shA/shB[buf2][ks2][256 rows][32 k] bf16 = 128 KiB total.
// Swizzle (T2): row of 32 bf16 = 4 chunks of 16B; LDS[row][c] holds global
//   chunk (c ^ ((row>>1)&3)).  Applied on the GLOBAL source address (DMA dest
//   stays linear, rule #21) and on the ds_read address.  Per 16-lane quarter
//   this leaves only a 2-way alias (free per m136).
// Pipeline (T3+T4): 4 phases per K-tile; each phase = {ds_read frags; stage
//   ONE half-slot 2x global_load_lds; s_barrier; setprio(1); 16 MFMA;
//   setprio(0); s_barrier}.  Stage targets a slot whose LAST ds_read was in
//   the previous phase (barrier-separated => race-free):
//     ph1 reads A[buf][0](all mi)+B[buf][0](ni01), stages B[buf^1][1] (t+1)
//     ph2 reads B[buf][0](ni23),                   stages A[buf][0]   (t+2)
//     ph3 reads A[buf][1]+B[buf][1](ni01),         stages B[buf][0]   (t+2)
//     ph4 reads B[buf][1](ni23),                   stages A[buf][1]   (t+2)
//   Tile boundary: ONE s_waitcnt vmcnt(6) (3 half-tiles = 6 loads in flight,
//   never 0 in steady state) + s_barrier.  Last boundary drains vmcnt(0).
template<int EPI, int KD_, int NT>
__global__ __launch_bounds__(512, 2)
void gemm_8ph(const ushort_t* __restrict__ A, const ushort_t* __restrict__ Bm,
              ushort_t* __restrict__ Cb, float* __restrict__ Cf,
              const float* __restrict__ X, const float* __restrict__ Dv) {
    __shared__ ushort_t shA[2][2][256 * 32];
    __shared__ ushort_t shB[2][2][256 * 32];
    constexpr int NKT = KD_ / 64;

    const int tid  = threadIdx.x;
    const int lane = tid & 63;
    const int wv   = tid >> 6;
    const int wr = wv >> 2, wc = wv & 3;
    const int l15 = lane & 15, lq = lane >> 4;

    // XCD swizzle: all NT n-tiles of an m-tile adjacent on one XCD.
    const int lin = blockIdx.x;
    const int xcd = lin & 7;
    const int j   = lin >> 3;
    const int mt  = xcd * 16 + j / NT;
    const int nt  = j % NT;
    const int m0 = mt * 256;
    const int n0 = nt * 256;
    const int CN = NT * 256;

    f32x4 acc[8][4];
#pragma unroll
    for (int i = 0; i < 8; ++i)
#pragma unroll
        for (int jj = 0; jj < 4; ++jj)
            acc[i][jj] = (f32x4){0.f, 0.f, 0.f, 0.f};

    // ---- staging addresses: thread -> (row, chunk) of a [256][32] slot.
    // LDS dest linear: wave wv, inst L -> rows (wv*2+L)*16 + lane/4,
    // chunk lane&3.  Global source pre-swizzled: chunk_g = (lane&3)^((lane>>3)&3).
    const int srow = wv * 32 + (lane >> 2);                      // L=0 row
    const int sck  = (((lane & 3) ^ ((lane >> 3) & 3))) * 8;     // ushorts
    const ushort_t* Ag = A  + (size_t)(m0 + srow) * KD_ + sck;
    const ushort_t* Bg = Bm + (size_t)(n0 + srow) * KD_ + sck;

#define STAGE_A(t, ks) do {                                                   \
        const ushort_t* g_ = Ag + (size_t)(t) * 64 + (ks) * 32;               \
        ushort_t* d_ = &shA[(t) & 1][(ks)][wv * 1024];                        \
        load16_lds(g_, d_);                                                   \
        load16_lds(g_ + (size_t)16 * KD_, d_ + 512);                          \
    } while (0)
#define STAGE_B(t, ks) do {                                                   \
        const ushort_t* g_ = Bg + (size_t)(t) * 64 + (ks) * 32;               \
        ushort_t* d_ = &shB[(t) & 1][(ks)][wv * 1024];                        \
        load16_lds(g_, d_);                                                   \
        load16_lds(g_ + (size_t)16 * KD_, d_ + 512);                          \
    } while (0)

    // ---- ds_read addressing (swizzled chunk = lq ^ ((l15>>1)&3)).
    const int rdoff = ((lq ^ ((l15 >> 1) & 3))) * 8;             // ushorts
    const int rdA = (wr * 128 + l15) * 32 + rdoff;               // + mi*512
    const int rdB = (wc * 64  + l15) * 32 + rdoff;               // + ni*512

#define MFMA_PH(bx, by, nlo) do {                                             \
        __builtin_amdgcn_s_setprio(1);                                        \
        _Pragma("unroll")                                                     \
        for (int mi_ = 0; mi_ < 8; ++mi_) {                                   \
            acc[mi_][nlo]     = __builtin_amdgcn_mfma_f32_16x16x32_bf16(      \
                af[mi_], bx, acc[mi_][nlo], 0, 0, 0);                         \
            acc[mi_][nlo + 1] = __builtin_amdgcn_mfma_f32_16x16x32_bf16(      \
                af[mi_], by, acc[mi_][nlo + 1], 0, 0, 0);                     \
        }                                                                     \
        __builtin_amdgcn_s_setprio(0);                                        \
    } while (0)

    // ---- prologue: tile0 fully + {A(1,0), B(1,0), A(1,1)} = 14 loads;
    // vmcnt(6) -> tile0's 8 loads landed, 3 half-tiles in flight.
    STAGE_A(0, 0); STAGE_A(0, 1); STAGE_B(0, 0); STAGE_B(0, 1);
    STAGE_A(1, 0); STAGE_B(1, 0); STAGE_A(1, 1);
    asm volatile("s_waitcnt vmcnt(6)" ::: "memory");
    __builtin_amdgcn_s_barrier();

    bf16x8 af[8];
#pragma unroll 2
    for (int kt = 0; kt < NKT; ++kt) {
        const int buf = kt & 1;
        const ushort_t* aS0 = &shA[buf][0][rdA];
        const ushort_t* aS1 = &shA[buf][1][rdA];
        const ushort_t* bS0 = &shB[buf][0][rdB];
        const ushort_t* bS1 = &shB[buf][1][rdB];

        { // ---- phase 1: ks0 x ni{0,1}
#pragma unroll
            for (int mi = 0; mi < 8; ++mi) af[mi] = ldfrag(aS0 + mi * 512);
            bf16x8 b0 = ldfrag(bS0), b1 = ldfrag(bS0 + 512);
            if (kt + 1 < NKT) STAGE_B(kt + 1, 1);
            __builtin_amdgcn_s_barrier();
            MFMA_PH(b0, b1, 0);
            __builtin_amdgcn_s_barrier();
        }
        { // ---- phase 2: ks0 x ni{2,3}
            bf16x8 b2 = ldfrag(bS0 + 1024), b3 = ldfrag(bS0 + 1536);
            if (kt + 2 < NKT) STAGE_A(kt + 2, 0);
            __builtin_amdgcn_s_barrier();
            MFMA_PH(b2, b3, 2);
            __builtin_amdgcn_s_barrier();
        }
        { // ---- phase 3: ks1 x ni{0,1}
#pragma unroll
            for (int mi = 0; mi < 8; ++mi) af[mi] = ldfrag(aS1 + mi * 512);
            bf16x8 b0 = ldfrag(bS1), b1 = ldfrag(bS1 + 512);
            if (kt + 2 < NKT) STAGE_B(kt + 2, 0);
            __builtin_amdgcn_s_barrier();
            MFMA_PH(b0, b1, 0);
            __builtin_amdgcn_s_barrier();
        }
        { // ---- phase 4: ks1 x ni{2,3} + tile boundary
            bf16x8 b2 = ldfrag(bS1 + 1024), b3 = ldfrag(bS1 + 1536);
            if (kt + 2 < NKT) STAGE_A(kt + 2, 1);
            __builtin_amdgcn_s_barrier();
            MFMA_PH(b2, b3, 2);
            if (kt + 1 < NKT) {
                if (kt + 2 < NKT)
                    asm volatile("s_waitcnt vmcnt(6)" ::: "memory");
                else
                    asm volatile("s_waitcnt vmcnt(0)" ::: "memory");
                __builtin_amdgcn_s_barrier();
            }
        }
    }
#undef STAGE_A
#undef STAGE_B
#undef MFMA_PH

    // ---- epilogue (same mapping as previous round, new geometry).
#pragma unroll
    for (int mi = 0; mi < 8; ++mi) {
#pragma unroll
        for (int ni = 0; ni < 4; ++ni) {
            const int col = n0 + wc * 64 + ni * 16 + l15;
            float dsum = 0.f;
            if (EPI == 1) dsum = Dv[col] + Dv[512 + col];
#pragma unroll
            for (int r = 0; r < 4; ++r) {
                const int row = m0 + wr * 128 + mi * 16 + lq * 4 + r;
                if (EPI == 0) {
                    Cb[(size_t)row * CN + col] = f2bf(acc[mi][ni][r]);
                } else {
                    const size_t idx = (size_t)row * 512 + col;
                    Cf[idx] = acc[mi][ni][r] + X[idx] * dsum;
                }
            }
        }
    }
}

// ---------------------------------------------------------------------------
// Scans unchanged from previous round.
__global__ __launch_bounds__(512)
void scan_carry(const ushort_t* __restrict__ S, const float* __restrict__ abar,
                float* __restrict__ carry) {
    int b = blockIdx.x, c = blockIdx.y, t = threadIdx.x;
    int dir = t >> 8, p = t & 255;
    float ar = abar[dir * 512 + 2 * p], ai = abar[dir * 512 + 2 * p + 1];
    float sr = 0.f, si = 0.f;
    const ushort_t* base = S + ((size_t)b * SEQ + (size_t)c * CH) * 1024
                             + dir * 512 + 2 * p;
    for (int ii = 0; ii < CH; ++ii) {
        int i = dir ? (CH - 1 - ii) : ii;
        unsigned u = *(const unsigned*)(base + (size_t)i * 1024);
        float re = bf2f((ushort_t)(u & 0xffffu));
        float im = bf2f((ushort_t)(u >> 16));
        float nr = fmaf(ar, sr, fmaf(-ai, si, re));
        float ni = fmaf(ar, si, fmaf(ai, sr, im));
        sr = nr; si = ni;
    }
    int o = (b * NC + c) * 1024 + dir * 512 + 2 * p;
    carry[o] = sr; carry[o + 1] = si;
}

__global__ __launch_bounds__(512)
void scan_comb(const float* __restrict__ carry, float* __restrict__ init,
               const float* __restrict__ apow) {
    int b = blockIdx.x, t = threadIdx.x;
    int dir = t >> 8, p = t & 255;
    float pr = apow[dir * 512 + 2 * p], pi = apow[dir * 512 + 2 * p + 1];
    float sr = 0.f, si = 0.f;
    for (int cc = 0; cc < NC; ++cc) {
        int c = dir ? (NC - 1 - cc) : cc;
        int o = (b * NC + c) * 1024 + dir * 512 + 2 * p;
        init[o] = sr; init[o + 1] = si;
        float cr = carry[o], ci = carry[o + 1];
        float nr = fmaf(pr, sr, fmaf(-pi, si, cr));
        float ni = fmaf(pr, si, fmaf(pi, sr, ci));
        sr = nr; si = ni;
    }
}

__global__ __launch_bounds__(512)
void scan_final(ushort_t* __restrict__ S, const float* __restrict__ abar,
                const float* __restrict__ init) {
    int b = blockIdx.x, c = blockIdx.y, t = threadIdx.x;
    int dir = t >> 8, p = t & 255;
    float ar = abar[dir * 512 + 2 * p], ai = abar[dir * 512 + 2 * p + 1];
    int o = (b * NC + c) * 1024 + dir * 512 + 2 * p;
    float sr = init[o], si = init[o + 1];
    ushort_t* base = S + ((size_t)b * SEQ + (size_t)c * CH) * 1024
                       + dir * 512 + 2 * p;
    for (int ii = 0; ii < CH; ++ii) {
        int i = dir ? (CH - 1 - ii) : ii;
        unsigned* addr = (unsigned*)(base + (size_t)i * 1024);
        unsigned u = *addr;
        float re = bf2f((ushort_t)(u & 0xffffu));
        float im = bf2f((ushort_t)(u >> 16));
        float nr = fmaf(ar, sr, fmaf(-ai, si, re));
        float ni = fmaf(ar, si, fmaf(ai, sr, im));
        sr = nr; si = ni;
        *addr = ((unsigned)f2bf(si) << 16) | (unsigned)f2bf(sr);
    }
}

// ---------------------------------------------------------------------------
// ws layout (bytes):
//  SB16 : 0           (67,108,864)  [M][1024] bf16 states both dirs
//  X16  : 67,108,864  (33,554,432)  bf16 x
//  Bm16 : 100,663,296 (1,048,576)
//  Cm16 : 101,711,872 (1,048,576)
//  abar : 102,760,448 (4,096)
//  apow : 102,764,544 (4,096)
//  carry: 67,108,864  (1,048,576)   alias over X16 head (dead after GEMM1)
//  init : 68,157,440  (1,048,576)   alias
extern "C" void kernel_launch(void* const* d_in, const int* in_sizes, int n_in,
                              void* d_out, int out_size, void* d_ws, size_t ws_size,
                              hipStream_t stream) {
    const float* x   = (const float*)d_in[0];
    const float* Lre = (const float*)d_in[1];
    const float* Lim = (const float*)d_in[2];
    const float* ldt = (const float*)d_in[3];
    const float* Bre = (const float*)d_in[4];
    const float* Bim = (const float*)d_in[5];
    const float* Cre = (const float*)d_in[6];
    const float* Cim = (const float*)d_in[7];
    const float* Dv  = (const float*)d_in[8];
    float* y = (float*)d_out;
    char* ws = (char*)d_ws;

    ushort_t* SB16 = (ushort_t*)(ws);
    ushort_t* X16  = (ushort_t*)(ws + 67108864);
    ushort_t* Bm16 = (ushort_t*)(ws + 100663296);
    ushort_t* Cm16 = (ushort_t*)(ws + 101711872);
    float* abar  = (float*)(ws + 102760448);
    float* apow  = (float*)(ws + 102764544);
    float* carry = (float*)(ws + 67108864);
    float* initb = (float*)(ws + 68157440);

    prep_kernel<<<1024, 256, 0, stream>>>(Lre, Lim, ldt, Bre, Bim, Cre, Cim,
                                          abar, apow, Bm16, Cm16);
    conv_x_kernel<<<16384, 256, 0, stream>>>(x, X16);

    // GEMM1: SB[M][1024] = X16[M][512] * Bm16[1024][512]^T  (128 mt x 4 nt)
    gemm_8ph<0, 512, 4><<<512, 512, 0, stream>>>(X16, Bm16, SB16, nullptr,
                                                 nullptr, nullptr);

    dim3 gs(B_SZ, NC);
    scan_carry<<<gs, 512, 0, stream>>>(SB16, abar, carry);
    scan_comb<<<B_SZ, 512, 0, stream>>>(carry, initb, apow);
    scan_final<<<gs, 512, 0, stream>>>(SB16, abar, initb);

    // GEMM2: y[M][512] = SB16[M][1024] * Cm16[512][1024]^T + x*(D0+D1)
    gemm_8ph<1, 1024, 2><<<256, 512, 0, stream>>>(SB16, Cm16, nullptr, y,
                                                  x, Dv);
}